// Round 5
// baseline (607.311 us; speedup 1.0000x reference)
//
#include <hip/hip_runtime.h>

// ---------------------------------------------------------------------------
// DeformableTransformer encoder layer, MI355X (gfx950).
// R5: deform_sample rewritten — 1 lane = 1 head (32 ch), fused softmax,
// division-free addressing, XCD-batch-affinity block swizzle (each batch's
// random gathers pinned to one XCD pair so its 6.7 MB value slice fits L2).
// ---------------------------------------------------------------------------

#define BLTOK 52500   // B*L tokens
#define MP    52608   // BLTOK padded to multiple of 128
#define LSP   13125   // L (spatial length per batch)

using short8  = __attribute__((ext_vector_type(8))) short;
using ushort8v= __attribute__((ext_vector_type(8))) unsigned short;
using f32x4   = __attribute__((ext_vector_type(4))) float;
using fl2     = __attribute__((ext_vector_type(2))) float;

__device__ __forceinline__ ushort f2b(float f) {
  union { float f; unsigned u; } x; x.f = f;
  unsigned r = (x.u + 0x7fffu + ((x.u >> 16) & 1u)) >> 16;
  return (ushort)r;
}
__device__ __forceinline__ float b2f(ushort h) {
  union { unsigned u; float f; } x; x.u = ((unsigned)h) << 16;
  return x.f;
}
__device__ __forceinline__ float lo16f(uint u) {
  union { unsigned u; float f; } x; x.u = u << 16; return x.f;
}
__device__ __forceinline__ float hi16f(uint u) {
  union { unsigned u; float f; } x; x.u = u & 0xffff0000u; return x.f;
}

#define GLDS16(gp, lp) __builtin_amdgcn_global_load_lds( \
    (const __attribute__((address_space(1))) void*)(gp), \
    (__attribute__((address_space(3))) void*)(lp), 16, 0, 0)

// ---------------- weight prep: transpose to N x K, convert bf16 -------------
__global__ __launch_bounds__(256) void prep_weights(
    const float* __restrict__ Wv, const float* __restrict__ Woff,
    const float* __restrict__ Wattn, const float* __restrict__ Wout,
    const float* __restrict__ Wff1, const float* __restrict__ Wff2,
    const float* __restrict__ boff, const float* __restrict__ battn,
    ushort* __restrict__ wv_t, ushort* __restrict__ wcat_t,
    ushort* __restrict__ wout_t, ushort* __restrict__ wff1_t,
    ushort* __restrict__ wff2_t, float* __restrict__ bcat)
{
  int i = blockIdx.x * 256 + threadIdx.x;
  if (i < 65536) {
    int n = i >> 8, k = i & 255;
    wv_t[i] = f2b(Wv[k * 256 + n]);
    return;
  }
  int j = i - 65536;
  if (j < 98304) {                       // 384 rows (320.. zero)
    int n = j >> 8, k = j & 255;
    float v = (n < 192) ? Woff[k * 192 + n]
            : (n < 288) ? Wattn[k * 96 + (n - 192)] : 0.f;
    wcat_t[j] = f2b(v);
    return;
  }
  j -= 98304;
  if (j < 65536) {
    int n = j >> 8, k = j & 255;
    wout_t[j] = f2b(Wout[k * 256 + n]);
    return;
  }
  j -= 65536;
  if (j < 262144) {
    int n = j >> 8, k = j & 255;
    wff1_t[j] = f2b(Wff1[k * 1024 + n]);
    return;
  }
  j -= 262144;
  if (j < 262144) {
    int n = j >> 10, k = j & 1023;
    wff2_t[j] = f2b(Wff2[k * 256 + n]);
    return;
  }
  j -= 262144;
  if (j < 384) bcat[j] = (j < 192) ? boff[j] : (j < 288) ? battn[j - 192] : 0.f;
}

// ---------------- activation prep: bf16 src and q=src+pos, zero pad rows ----
__global__ __launch_bounds__(256) void prep_act(
    const float* __restrict__ src, const float* __restrict__ pos,
    ushort* __restrict__ src_bf, ushort* __restrict__ q_bf)
{
  const size_t e = ((size_t)blockIdx.x * 256 + threadIdx.x) * 4;
  if (e >= (size_t)MP * 256) return;
  ushort4 sb, qb;
  if (e < (size_t)BLTOK * 256) {
    const float4 s = *(const float4*)(src + e);
    const float4 p = *(const float4*)(pos + e);
    sb.x = f2b(s.x); sb.y = f2b(s.y); sb.z = f2b(s.z); sb.w = f2b(s.w);
    qb.x = f2b(s.x + p.x); qb.y = f2b(s.y + p.y);
    qb.z = f2b(s.z + p.z); qb.w = f2b(s.w + p.w);
  } else {
    sb.x = sb.y = sb.z = sb.w = 0;
    qb.x = qb.y = qb.z = qb.w = 0;
  }
  *(ushort4*)(src_bf + e) = sb;
  *(ushort4*)(q_bf + e) = qb;
}

// ---------------- GEMM 128x128, dbuf GLDS staging, coalesced epilogue -------
// grid = (Ntiles, Mtiles). EPI: 0 = bias; 1 = +addf(f32); 2 = relu; 3 = +addb(bf16)
template <int EPI>
__global__ __launch_bounds__(256) void gemm128(
    const ushort* __restrict__ A, const ushort* __restrict__ Bt,
    const float* __restrict__ bias, const float* __restrict__ addf,
    const ushort* __restrict__ addb, ushort* __restrict__ C,
    int Mact, int Nact, int Nstr, int K)
{
  __shared__ __align__(16) ushort sm[16384];     // 32 KB
  ushort* As = sm;                               // [2][4096]
  ushort* Bs = sm + 8192;                        // [2][4096]
  float*  epf = (float*)sm;                      // epilogue: 64 x 128 f32
  const int tid = threadIdx.x;
  const int wave = tid >> 6, lane = tid & 63;
  const int n0 = blockIdx.x * 128, m0 = blockIdx.y * 128;
  const int srow = lane >> 2, skc = (lane & 3) * 8;
  const ushort* Ag = A + (size_t)(m0 + wave * 32 + srow) * K + skc;
  const ushort* Bg = Bt + (size_t)(n0 + wave * 32 + srow) * K + skc;
  const int quad = lane >> 4, l16 = lane & 15;
  const int wm = (wave & 1) * 64, wn = (wave >> 1) * 64;
  f32x4 acc[4][4] = {};

#define STAGE(buf, kk) { \
    ushort* la = As + (buf) * 4096 + wave * 1024; \
    ushort* lb = Bs + (buf) * 4096 + wave * 1024; \
    GLDS16(Ag + (kk), la); \
    GLDS16(Ag + (kk) + 16 * K, la + 512); \
    GLDS16(Bg + (kk), lb); \
    GLDS16(Bg + (kk) + 16 * K, lb + 512); }

  STAGE(0, 0);
  int cur = 0;
  for (int k0 = 0; k0 < K; k0 += 32) {
    __syncthreads();
    if (k0 + 32 < K) STAGE(cur ^ 1, k0 + 32);
    const ushort* Ab = As + cur * 4096;
    const ushort* Bb = Bs + cur * 4096;
    short8 af[4], bf[4];
#pragma unroll
    for (int i = 0; i < 4; i++)
      af[i] = *(const short8*)(&Ab[(wm + i * 16 + l16) * 32 + quad * 8]);
#pragma unroll
    for (int j = 0; j < 4; j++)
      bf[j] = *(const short8*)(&Bb[(wn + j * 16 + l16) * 32 + quad * 8]);
#pragma unroll
    for (int i = 0; i < 4; i++)
#pragma unroll
      for (int j = 0; j < 4; j++)
        acc[i][j] = __builtin_amdgcn_mfma_f32_16x16x32_bf16(af[i], bf[j],
                                                            acc[i][j], 0, 0, 0);
    cur ^= 1;
  }
#undef STAGE

  for (int half = 0; half < 2; half++) {
    __syncthreads();
    if ((wave & 1) == half) {
#pragma unroll
      for (int i = 0; i < 4; i++)
#pragma unroll
        for (int j = 0; j < 4; j++)
#pragma unroll
          for (int r = 0; r < 4; r++)
            epf[(i * 16 + quad * 4 + r) * 128 + wn + j * 16 + l16] = acc[i][j][r];
    }
    __syncthreads();
    const int gm0 = m0 + half * 64;
#pragma unroll
    for (int g = 0; g < 4; g++) {
      const int lrow = g * 16 + (tid >> 4);
      const int col0 = (tid & 15) * 8;
      const int grow = gm0 + lrow;
      const int gcol = n0 + col0;
      if (grow < Mact && gcol < Nact) {
        float v[8];
#pragma unroll
        for (int c = 0; c < 8; c++) v[c] = epf[lrow * 128 + col0 + c] + bias[gcol + c];
        const size_t idx = (size_t)grow * Nstr + gcol;
        if (EPI == 1) {
          const float4 a0 = *(const float4*)(addf + idx);
          const float4 a1 = *(const float4*)(addf + idx + 4);
          v[0] += a0.x; v[1] += a0.y; v[2] += a0.z; v[3] += a0.w;
          v[4] += a1.x; v[5] += a1.y; v[6] += a1.z; v[7] += a1.w;
        }
        if (EPI == 2) {
#pragma unroll
          for (int c = 0; c < 8; c++) v[c] = fmaxf(v[c], 0.f);
        }
        if (EPI == 3) {
          const ushort8v ab = *(const ushort8v*)(addb + idx);
#pragma unroll
          for (int c = 0; c < 8; c++) v[c] += b2f(ab[c]);
        }
        ushort8v o;
#pragma unroll
        for (int c = 0; c < 8; c++) o[c] = f2b(v[c]);
        *(ushort8v*)(C + idx) = o;
      }
    }
  }
}

// ---------------- MS-deform-attn core: 1 lane = 1 head (32 ch) --------------
// Softmax over the head's 12 logits fused in-register. Division-free address
// math: (ref + off/W)*W - 0.5 == ref*W + off - 0.5. XCD-batch affinity:
// XCD = blockIdx&7 (dispatch heuristic); batch = XCD/2 so each batch's 6.7 MB
// value slice lives in one XCD pair's 8 MB of L2.
__global__ __launch_bounds__(256) void deform_sample(
    const ushort* __restrict__ value, const ushort* __restrict__ oa_all,
    const float* __restrict__ refp, ushort* __restrict__ outb)
{
  const int tid = threadIdx.x;
  const int g = blockIdx.x & 7, j = blockIdx.x >> 3;   // 8 x 206 blocks
  const int batch = g >> 1;
  const int tin = ((g & 1) * 206 + j) * 32 + (tid >> 3);
  if (tin >= LSP) return;
  const int tok = batch * LSP + tin;
  const int h = tid & 7;
  const ushort* oa = oa_all + (size_t)tok * 320;
  // offsets: 24 ushorts at oa + h*24 (16B-aligned); logits: 12 at oa+192+h*12
  uint offv[12];
  {
    const uint4 o0 = *(const uint4*)(oa + h * 24);
    const uint4 o1 = *(const uint4*)(oa + h * 24 + 8);
    const uint4 o2 = *(const uint4*)(oa + h * 24 + 16);
    offv[0] = o0.x; offv[1] = o0.y; offv[2] = o0.z; offv[3] = o0.w;
    offv[4] = o1.x; offv[5] = o1.y; offv[6] = o1.z; offv[7] = o1.w;
    offv[8] = o2.x; offv[9] = o2.y; offv[10] = o2.z; offv[11] = o2.w;
  }
  float wsm[12];
  {
    const ushort* lg = oa + 192 + h * 12;
    const uint2 l0 = *(const uint2*)(lg);
    const uint2 l1 = *(const uint2*)(lg + 4);
    const uint2 l2 = *(const uint2*)(lg + 8);
    wsm[0] = lo16f(l0.x); wsm[1] = hi16f(l0.x);
    wsm[2] = lo16f(l0.y); wsm[3] = hi16f(l0.y);
    wsm[4] = lo16f(l1.x); wsm[5] = hi16f(l1.x);
    wsm[6] = lo16f(l1.y); wsm[7] = hi16f(l1.y);
    wsm[8] = lo16f(l2.x); wsm[9] = hi16f(l2.x);
    wsm[10] = lo16f(l2.y); wsm[11] = hi16f(l2.y);
    float mx = wsm[0];
#pragma unroll
    for (int i = 1; i < 12; i++) mx = fmaxf(mx, wsm[i]);
    float s = 0.f;
#pragma unroll
    for (int i = 0; i < 12; i++) { wsm[i] = __expf(wsm[i] - mx); s += wsm[i]; }
    const float inv = 1.f / s;
#pragma unroll
    for (int i = 0; i < 12; i++) wsm[i] *= inv;
  }
  const float* rp = refp + (size_t)tok * 6;
  const uint vbase = (uint)batch * (LSP * 256u) + (uint)(h * 32);
  const int Wl[3] = {100, 50, 25};
  const int Stl[3] = {0, 10000, 12500};
  fl2 acc2[16] = {};
#pragma unroll
  for (int lid = 0; lid < 3; lid++) {
    const int W = Wl[lid], st = Stl[lid];   // square levels: H == W
    const float Wf = (float)W;
    const float bx = rp[lid * 2] * Wf - 0.5f;
    const float by = rp[lid * 2 + 1] * Wf - 0.5f;
#pragma unroll
    for (int p = 0; p < 4; p++) {
      const uint oxy = offv[lid * 4 + p];
      const float x = bx + lo16f(oxy);
      const float y = by + hi16f(oxy);
      const float aw = wsm[lid * 4 + p];
      const float x0f = floorf(x), y0f = floorf(y);
      const float wx1 = x - x0f, wy1 = y - y0f;
      const float wx0 = 1.f - wx1, wy0 = 1.f - wy1;
      const int ix0 = (int)x0f, iy0 = (int)y0f;
      const bool x0v = (ix0 >= 0) & (ix0 < W);
      const bool x1v = (ix0 + 1 >= 0) & (ix0 + 1 < W);
      const bool y0v = (iy0 >= 0) & (iy0 < W);
      const bool y1v = (iy0 + 1 >= 0) & (iy0 + 1 < W);
      const float ay0 = aw * wy0, ay1 = aw * wy1;
      const float w00 = (x0v & y0v) ? ay0 * wx0 : 0.f;
      const float w10 = (x1v & y0v) ? ay0 * wx1 : 0.f;
      const float w01 = (x0v & y1v) ? ay1 * wx0 : 0.f;
      const float w11 = (x1v & y1v) ? ay1 * wx1 : 0.f;
      const int ix0c = min(max(ix0, 0), W - 1);
      const int ix1c = min(max(ix0 + 1, 0), W - 1);
      const int iy0c = min(max(iy0, 0), W - 1);
      const int iy1c = min(max(iy0 + 1, 0), W - 1);
      const uint r00 = vbase + (uint)(st + iy0c * W + ix0c) * 256u;
      const uint r10 = vbase + (uint)(st + iy0c * W + ix1c) * 256u;
      const uint r01 = vbase + (uint)(st + iy1c * W + ix0c) * 256u;
      const uint r11 = vbase + (uint)(st + iy1c * W + ix1c) * 256u;
      uint4 q00[2], q10[2], q01[2], q11[2];
#pragma unroll
      for (int c = 0; c < 2; c++) {
        q00[c] = *(const uint4*)(value + r00 + c * 8);
        q10[c] = *(const uint4*)(value + r10 + c * 8);
        q01[c] = *(const uint4*)(value + r01 + c * 8);
        q11[c] = *(const uint4*)(value + r11 + c * 8);
      }
      const fl2 w00v = {w00, w00}, w10v = {w10, w10};
      const fl2 w01v = {w01, w01}, w11v = {w11, w11};
      const uint* u00 = (const uint*)q00;
      const uint* u10 = (const uint*)q10;
      const uint* u01 = (const uint*)q01;
      const uint* u11 = (const uint*)q11;
#pragma unroll
      for (int d = 0; d < 8; d++) {
        fl2 v00 = {lo16f(u00[d]), hi16f(u00[d])};
        fl2 v10 = {lo16f(u10[d]), hi16f(u10[d])};
        fl2 v01 = {lo16f(u01[d]), hi16f(u01[d])};
        fl2 v11 = {lo16f(u11[d]), hi16f(u11[d])};
        acc2[d] += w00v * v00 + w10v * v10 + w01v * v01 + w11v * v11;
      }
      uint4 q00b[2], q10b[2], q01b[2], q11b[2];
#pragma unroll
      for (int c = 0; c < 2; c++) {
        q00b[c] = *(const uint4*)(value + r00 + 16 + c * 8);
        q10b[c] = *(const uint4*)(value + r10 + 16 + c * 8);
        q01b[c] = *(const uint4*)(value + r01 + 16 + c * 8);
        q11b[c] = *(const uint4*)(value + r11 + 16 + c * 8);
      }
      const uint* v00p = (const uint*)q00b;
      const uint* v10p = (const uint*)q10b;
      const uint* v01p = (const uint*)q01b;
      const uint* v11p = (const uint*)q11b;
#pragma unroll
      for (int d = 0; d < 8; d++) {
        fl2 v00 = {lo16f(v00p[d]), hi16f(v00p[d])};
        fl2 v10 = {lo16f(v10p[d]), hi16f(v10p[d])};
        fl2 v01 = {lo16f(v01p[d]), hi16f(v01p[d])};
        fl2 v11 = {lo16f(v11p[d]), hi16f(v11p[d])};
        acc2[8 + d] += w00v * v00 + w10v * v10 + w01v * v01 + w11v * v11;
      }
    }
  }
  uint ov[16];
#pragma unroll
  for (int d = 0; d < 16; d++)
    ov[d] = (uint)f2b(acc2[d].x) | ((uint)f2b(acc2[d].y) << 16);
  ushort* op = outb + (size_t)tok * 256 + h * 32;
  *(uint4*)(op) = *(uint4*)(ov);
  *(uint4*)(op + 8) = *(uint4*)(ov + 4);
  *(uint4*)(op + 16) = *(uint4*)(ov + 8);
  *(uint4*)(op + 24) = *(uint4*)(ov + 12);
}

// ---------------- LayerNorm over 256 (wave per row, 4 rows/block) -----------
template <int OUTF>
__global__ __launch_bounds__(256) void ln256(
    const ushort* __restrict__ in, const float* __restrict__ gg,
    const float* __restrict__ bb, ushort* __restrict__ outb,
    float* __restrict__ outf, int rows)
{
  const int wave = threadIdx.x >> 6, lane = threadIdx.x & 63;
  const int r = blockIdx.x * 4 + wave;
  if (r >= rows) return;
  const ushort* rowp = in + (size_t)r * 256;
  const ushort4 u = *(const ushort4*)(rowp + lane * 4);
  float v[4] = {b2f(u.x), b2f(u.y), b2f(u.z), b2f(u.w)};
  float s = v[0] + v[1] + v[2] + v[3];
  float s2 = v[0] * v[0] + v[1] * v[1] + v[2] * v[2] + v[3] * v[3];
#pragma unroll
  for (int o = 32; o > 0; o >>= 1) {
    s += __shfl_xor(s, o);
    s2 += __shfl_xor(s2, o);
  }
  const float mean = s * (1.f / 256.f);
  const float var = s2 * (1.f / 256.f) - mean * mean;
  const float rstd = rsqrtf(var + 1e-5f);
#pragma unroll
  for (int j = 0; j < 4; j++) {
    const int col = lane * 4 + j;
    const float o = (v[j] - mean) * rstd * gg[col] + bb[col];
    if (OUTF) outf[(size_t)r * 256 + col] = o;
    else outb[(size_t)r * 256 + col] = f2b(o);
  }
}

// ---------------------------------------------------------------------------
extern "C" void kernel_launch(void* const* d_in, const int* in_sizes, int n_in,
                              void* d_out, int out_size, void* d_ws, size_t ws_size,
                              hipStream_t stream)
{
  const float* src   = (const float*)d_in[0];
  const float* pos   = (const float*)d_in[1];
  const float* refp  = (const float*)d_in[2];
  const float* Wv    = (const float*)d_in[3];
  const float* bv    = (const float*)d_in[4];
  const float* Woff  = (const float*)d_in[5];
  const float* boff  = (const float*)d_in[6];
  const float* Wattn = (const float*)d_in[7];
  const float* battn = (const float*)d_in[8];
  const float* Wout  = (const float*)d_in[9];
  const float* bout  = (const float*)d_in[10];
  const float* g1    = (const float*)d_in[11];
  const float* b1    = (const float*)d_in[12];
  const float* Wff1  = (const float*)d_in[13];
  const float* bff1  = (const float*)d_in[14];
  const float* Wff2  = (const float*)d_in[15];
  const float* bff2  = (const float*)d_in[16];
  const float* g2    = (const float*)d_in[17];
  const float* b2    = (const float*)d_in[18];
  float* out = (float*)d_out;
  char* ws = (char*)d_ws;

  ushort* wcat_t = (ushort*)(ws + 0);            //   196608 (384 x 256)
  ushort* wff1_t = (ushort*)(ws + 196608);       //   524288
  ushort* wff2_t = (ushort*)(ws + 720896);       //   524288
  float*  bcat   = (float*)(ws + 1245184);       //     1536
  ushort* A1 = (ushort*)(ws + 1246720);          // src_bf (lives to G3)
  ushort* A2 = (ushort*)(ws + 28182016);         // q_bf -> x_bf
  ushort* A3 = (ushort*)(ws + 55117312);         // value -> y_bf
  ushort* A4 = (ushort*)(ws + 81997312);         // offattn(320) -> xpre(256)
  ushort* A5 = (ushort*)(ws + 115597312);        // attn_out (head) -> h (MPx1024)
  ushort* wout_t = (ushort*)(ws + 223076352);    //   131072 (A5 tail)
  ushort* wv_t   = (ushort*)(ws + 223207424);    //   131072 (A5 tail)

  prep_weights<<<2946, 256, 0, stream>>>(Wv, Woff, Wattn, Wout, Wff1, Wff2,
                                         boff, battn,
                                         wv_t, wcat_t, wout_t, wff1_t, wff2_t, bcat);
  prep_act<<<MP / 4, 256, 0, stream>>>(src, pos, A1, A2);
  // G1: value = src @ Wv + bv
  gemm128<0><<<dim3(2, MP / 128), 256, 0, stream>>>(A1, wv_t, bv, nullptr, nullptr,
                                                    A3, BLTOK, 256, 256, 256);
  // G2: offattn = q @ Wcat + bcat  (N=320, tiles to 384)
  gemm128<0><<<dim3(3, MP / 128), 256, 0, stream>>>(A2, wcat_t, bcat, nullptr, nullptr,
                                                    A4, BLTOK, 320, 320, 256);
  // deform (softmax fused) -> attn_out in A5 head
  deform_sample<<<8 * 206, 256, 0, stream>>>(A3, A4, refp, A5);
  // G3: xpre = src_bf + attn_out @ Wout + bout
  gemm128<3><<<dim3(2, MP / 128), 256, 0, stream>>>(A5, wout_t, bout, nullptr, A1,
                                                    A4, BLTOK, 256, 256, 256);
  ln256<0><<<BLTOK / 4, 256, 0, stream>>>(A4, g1, b1, A2, nullptr, BLTOK);
  // G4: h = relu(x @ Wff1 + bff1) — store pad rows too (A2 pads are zero)
  gemm128<2><<<dim3(8, MP / 128), 256, 0, stream>>>(A2, wff1_t, bff1, nullptr, nullptr,
                                                    A5, MP, 1024, 1024, 256);
  // G5: y = x + h @ Wff2 + bff2
  gemm128<3><<<dim3(2, MP / 128), 256, 0, stream>>>(A5, wff2_t, bff2, nullptr, A2,
                                                    A3, BLTOK, 256, 256, 1024);
  ln256<1><<<BLTOK / 4, 256, 0, stream>>>(A3, g2, b2, nullptr, out, BLTOK);
}

// Round 6
// 488.439 us; speedup vs baseline: 1.2434x; 1.2434x over previous
//
#include <hip/hip_runtime.h>

// ---------------------------------------------------------------------------
// DeformableTransformer encoder layer, MI355X (gfx950).
// R6: deform reverted to R4 shape (8ch/lane, high TLP) + division-free math;
// GEMM -> 64x256 tile (full-N chunks: A fetched once), dbuf global_load_lds,
// coalesced f32-LDS epilogue.
// ---------------------------------------------------------------------------

#define BLTOK 52500   // B*L tokens
#define MPAD  52544   // BLTOK padded to multiple of 64
#define LSP   13125   // L (spatial length per batch)

using short8  = __attribute__((ext_vector_type(8))) short;
using ushort8v= __attribute__((ext_vector_type(8))) unsigned short;
using f32x4   = __attribute__((ext_vector_type(4))) float;
using fl2     = __attribute__((ext_vector_type(2))) float;

__device__ __forceinline__ ushort f2b(float f) {
  union { float f; unsigned u; } x; x.f = f;
  unsigned r = (x.u + 0x7fffu + ((x.u >> 16) & 1u)) >> 16;
  return (ushort)r;
}
__device__ __forceinline__ float b2f(ushort h) {
  union { unsigned u; float f; } x; x.u = ((unsigned)h) << 16;
  return x.f;
}
__device__ __forceinline__ float lo16f(uint u) {
  union { unsigned u; float f; } x; x.u = u << 16; return x.f;
}
__device__ __forceinline__ float hi16f(uint u) {
  union { unsigned u; float f; } x; x.u = u & 0xffff0000u; return x.f;
}

#define GLDS16(gp, lp) __builtin_amdgcn_global_load_lds( \
    (const __attribute__((address_space(1))) void*)(gp), \
    (__attribute__((address_space(3))) void*)(lp), 16, 0, 0)

// ---------------- weight prep: transpose to N x K, convert bf16 -------------
__global__ __launch_bounds__(256) void prep_weights(
    const float* __restrict__ Wv, const float* __restrict__ Woff,
    const float* __restrict__ Wattn, const float* __restrict__ Wout,
    const float* __restrict__ Wff1, const float* __restrict__ Wff2,
    const float* __restrict__ boff, const float* __restrict__ battn,
    ushort* __restrict__ wv_t, ushort* __restrict__ wcat_t,
    ushort* __restrict__ wout_t, ushort* __restrict__ wff1_t,
    ushort* __restrict__ wff2_t, float* __restrict__ bcat)
{
  int i = blockIdx.x * 256 + threadIdx.x;
  if (i < 65536) {
    int n = i >> 8, k = i & 255;
    wv_t[i] = f2b(Wv[k * 256 + n]);
    return;
  }
  int j = i - 65536;
  if (j < 98304) {                       // 384 rows (320.. zero)
    int n = j >> 8, k = j & 255;
    float v = (n < 192) ? Woff[k * 192 + n]
            : (n < 288) ? Wattn[k * 96 + (n - 192)] : 0.f;
    wcat_t[j] = f2b(v);
    return;
  }
  j -= 98304;
  if (j < 65536) {
    int n = j >> 8, k = j & 255;
    wout_t[j] = f2b(Wout[k * 256 + n]);
    return;
  }
  j -= 65536;
  if (j < 262144) {
    int n = j >> 8, k = j & 255;
    wff1_t[j] = f2b(Wff1[k * 1024 + n]);
    return;
  }
  j -= 262144;
  if (j < 262144) {
    int n = j >> 10, k = j & 1023;
    wff2_t[j] = f2b(Wff2[k * 256 + n]);
    return;
  }
  j -= 262144;
  if (j < 384) bcat[j] = (j < 192) ? boff[j] : (j < 288) ? battn[j - 192] : 0.f;
}

// ---------------- activation prep: bf16 src and q=src+pos (BLTOK rows) ------
__global__ __launch_bounds__(256) void prep_act(
    const float* __restrict__ src, const float* __restrict__ pos,
    ushort* __restrict__ src_bf, ushort* __restrict__ q_bf)
{
  const size_t e = ((size_t)blockIdx.x * 256 + threadIdx.x) * 4;
  const float4 s = *(const float4*)(src + e);
  const float4 p = *(const float4*)(pos + e);
  ushort4 sb, qb;
  sb.x = f2b(s.x); sb.y = f2b(s.y); sb.z = f2b(s.z); sb.w = f2b(s.w);
  qb.x = f2b(s.x + p.x); qb.y = f2b(s.y + p.y);
  qb.z = f2b(s.z + p.z); qb.w = f2b(s.w + p.w);
  *(ushort4*)(src_bf + e) = sb;
  *(ushort4*)(q_bf + e) = qb;
}

// ---------------- GEMM 64x256 tile: C = A @ Bt^T + bias ---------------------
// grid = (Nchunks, Mtiles64). Each block: 64 rows x 256 cols, K-contraction.
// Wave w: rows 0..63, cols w*64..w*64+63 -> acc[4][4]. A fetched once per
// chunk. Garbage A-rows beyond Mact are read but their outputs masked.
// EPI: 0 = bias; 2 = relu; 3 = + addb(bf16)
template <int EPI>
__global__ __launch_bounds__(256) void gemm64n(
    const ushort* __restrict__ A, const ushort* __restrict__ Bt,
    const float* __restrict__ bias, const ushort* __restrict__ addb,
    ushort* __restrict__ C, int Mact, int Nact, int Nstr, int K)
{
  __shared__ __align__(16) ushort sm[20480];     // 40 KB
  ushort* As = sm;                               // [2][64][32]
  ushort* Bs = sm + 4096;                        // [2][256][32]
  float*  epf = (float*)sm;                      // epilogue: 32 x 256 f32
  const int tid = threadIdx.x;
  const int wave = tid >> 6, lane = tid & 63;
  const int n0 = blockIdx.x * 256, m0 = blockIdx.y * 64;
  const int srow = lane >> 2, skc = (lane & 3) * 8;
  const ushort* Ag = A + (size_t)(m0 + wave * 16 + srow) * K + skc;
  const ushort* Bg = Bt + (size_t)(n0 + wave * 64 + srow) * K + skc;
  const int quad = lane >> 4, l16 = lane & 15;
  const int wn = wave * 64;
  f32x4 acc[4][4] = {};

#define STAGE(buf, kk) { \
    ushort* la = As + (buf) * 2048 + wave * 512; \
    ushort* lb = Bs + (buf) * 8192 + wave * 2048; \
    GLDS16(Ag + (kk), la); \
    GLDS16(Bg + (kk), lb); \
    GLDS16(Bg + (kk) + 16 * K, lb + 512); \
    GLDS16(Bg + (kk) + 32 * K, lb + 1024); \
    GLDS16(Bg + (kk) + 48 * K, lb + 1536); }

  STAGE(0, 0);
  int cur = 0;
  for (int k0 = 0; k0 < K; k0 += 32) {
    __syncthreads();
    if (k0 + 32 < K) STAGE(cur ^ 1, k0 + 32);
    const ushort* Ab = As + cur * 2048;
    const ushort* Bb = Bs + cur * 8192;
    short8 af[4], bf[4];
#pragma unroll
    for (int i = 0; i < 4; i++)
      af[i] = *(const short8*)(&Ab[(i * 16 + l16) * 32 + quad * 8]);
#pragma unroll
    for (int j = 0; j < 4; j++)
      bf[j] = *(const short8*)(&Bb[(wn + j * 16 + l16) * 32 + quad * 8]);
#pragma unroll
    for (int i = 0; i < 4; i++)
#pragma unroll
      for (int j = 0; j < 4; j++)
        acc[i][j] = __builtin_amdgcn_mfma_f32_16x16x32_bf16(af[i], bf[j],
                                                            acc[i][j], 0, 0, 0);
    cur ^= 1;
  }
#undef STAGE

  // epilogue: 2 rounds of 32 rows through f32 LDS, coalesced 16B stores
  for (int q = 0; q < 2; q++) {
    __syncthreads();
    // C/D: col = l16, row = quad*4 + r  [m89/m91]; round q takes i = 2q, 2q+1
#pragma unroll
    for (int ii = 0; ii < 2; ii++) {
      const int i = q * 2 + ii;
#pragma unroll
      for (int j = 0; j < 4; j++)
#pragma unroll
        for (int r = 0; r < 4; r++)
          epf[(ii * 16 + quad * 4 + r) * 256 + wn + j * 16 + l16] = acc[i][j][r];
    }
    __syncthreads();
#pragma unroll
    for (int g = 0; g < 4; g++) {
      const int lrow = g * 8 + (tid >> 5);
      const int col0 = (tid & 31) * 8;
      const int grow = m0 + q * 32 + lrow;
      const int gcol = n0 + col0;
      if (grow < Mact && gcol < Nact) {
        float v[8];
#pragma unroll
        for (int c = 0; c < 8; c++) v[c] = epf[lrow * 256 + col0 + c] + bias[gcol + c];
        const size_t idx = (size_t)grow * Nstr + gcol;
        if (EPI == 2) {
#pragma unroll
          for (int c = 0; c < 8; c++) v[c] = fmaxf(v[c], 0.f);
        }
        if (EPI == 3) {
          const ushort8v ab = *(const ushort8v*)(addb + idx);
#pragma unroll
          for (int c = 0; c < 8; c++) v[c] += b2f(ab[c]);
        }
        ushort8v o;
#pragma unroll
        for (int c = 0; c < 8; c++) o[c] = f2b(v[c]);
        *(ushort8v*)(C + idx) = o;
      }
    }
  }
}

// ---------------- softmax over 12 attn logits per (token, head), in place ---
__global__ __launch_bounds__(256) void softmax12(ushort* __restrict__ offattn)
{
  const int t = blockIdx.x * 256 + threadIdx.x;
  if (t >= BLTOK * 8) return;
  const int r = t >> 3, h = t & 7;
  ushort* p = offattn + (size_t)r * 320 + 192 + h * 12;
  float v[12], mx = -1e30f;
#pragma unroll
  for (int i = 0; i < 12; i++) { v[i] = b2f(p[i]); mx = fmaxf(mx, v[i]); }
  float s = 0.f;
#pragma unroll
  for (int i = 0; i < 12; i++) { v[i] = __expf(v[i] - mx); s += v[i]; }
  const float inv = 1.f / s;
#pragma unroll
  for (int i = 0; i < 12; i++) p[i] = f2b(v[i] * inv);
}

// ---------------- MS-deform-attn bilinear sampling (R4 shape) ---------------
// 32 lanes/token: lane l -> head h=l>>2, 8 channels. Division-free addressing.
__global__ __launch_bounds__(256) void deform_sample(
    const ushort* __restrict__ value, const ushort* __restrict__ oa_all,
    const float* __restrict__ refp, ushort* __restrict__ outb)
{
  const int tid = threadIdx.x;
  const int tok = blockIdx.x * 8 + (tid >> 5);
  if (tok >= BLTOK) return;
  const int b = tok / LSP;
  const int l = tid & 31;
  const int h = l >> 2;
  const ushort* oa = oa_all + (uint)tok * 320u;
  const float* rp = refp + (uint)tok * 6u;
  const uint base = (uint)b * (LSP * 256u) + (uint)(l * 8);
  const int Wl[3] = {100, 50, 25};
  const int Stl[3] = {0, 10000, 12500};
  fl2 acc2[4] = {};
#pragma unroll
  for (int lid = 0; lid < 3; lid++) {
    const int W = Wl[lid], st = Stl[lid];   // square levels: H == W
    const float Wf = (float)W;
    const float bx = rp[lid * 2] * Wf - 0.5f;       // (ref + off/W)*W - 0.5
    const float by = rp[lid * 2 + 1] * Wf - 0.5f;   //  == ref*W + off - 0.5
#pragma unroll
    for (int p = 0; p < 4; p++) {
      const uint oxy = *(const uint*)(oa + h * 24 + lid * 8 + p * 2);
      const float aw = b2f(oa[192 + h * 12 + lid * 4 + p]);
      const float x = bx + lo16f(oxy);
      const float y = by + hi16f(oxy);
      const float x0f = floorf(x), y0f = floorf(y);
      const float wx1 = x - x0f, wy1 = y - y0f;
      const float wx0 = 1.f - wx1, wy0 = 1.f - wy1;
      const int ix0 = (int)x0f, iy0 = (int)y0f;
      const bool x0v = (ix0 >= 0) & (ix0 < W);
      const bool x1v = (ix0 + 1 >= 0) & (ix0 + 1 < W);
      const bool y0v = (iy0 >= 0) & (iy0 < W);
      const bool y1v = (iy0 + 1 >= 0) & (iy0 + 1 < W);
      const float ay0 = aw * wy0, ay1 = aw * wy1;
      const float w00 = (x0v & y0v) ? ay0 * wx0 : 0.f;
      const float w10 = (x1v & y0v) ? ay0 * wx1 : 0.f;
      const float w01 = (x0v & y1v) ? ay1 * wx0 : 0.f;
      const float w11 = (x1v & y1v) ? ay1 * wx1 : 0.f;
      const int ix0c = min(max(ix0, 0), W - 1);
      const int ix1c = min(max(ix0 + 1, 0), W - 1);
      const int iy0c = min(max(iy0, 0), W - 1);
      const int iy1c = min(max(iy0 + 1, 0), W - 1);
      const uint r00 = (uint)(st + iy0c * W + ix0c) * 256u;
      const uint r10 = (uint)(st + iy0c * W + ix1c) * 256u;
      const uint r01 = (uint)(st + iy1c * W + ix0c) * 256u;
      const uint r11 = (uint)(st + iy1c * W + ix1c) * 256u;
      const uint4 q00 = *(const uint4*)(value + base + r00);
      const uint4 q10 = *(const uint4*)(value + base + r10);
      const uint4 q01 = *(const uint4*)(value + base + r01);
      const uint4 q11 = *(const uint4*)(value + base + r11);
      const fl2 w00v = {w00, w00}, w10v = {w10, w10};
      const fl2 w01v = {w01, w01}, w11v = {w11, w11};
      const uint* u00 = (const uint*)&q00;
      const uint* u10 = (const uint*)&q10;
      const uint* u01 = (const uint*)&q01;
      const uint* u11 = (const uint*)&q11;
#pragma unroll
      for (int pp = 0; pp < 4; pp++) {
        fl2 v00 = {lo16f(u00[pp]), hi16f(u00[pp])};
        fl2 v10 = {lo16f(u10[pp]), hi16f(u10[pp])};
        fl2 v01 = {lo16f(u01[pp]), hi16f(u01[pp])};
        fl2 v11 = {lo16f(u11[pp]), hi16f(u11[pp])};
        acc2[pp] += w00v * v00 + w10v * v10 + w01v * v01 + w11v * v11;
      }
    }
  }
  ushort4 o0, o1;
  o0.x = f2b(acc2[0].x); o0.y = f2b(acc2[0].y);
  o0.z = f2b(acc2[1].x); o0.w = f2b(acc2[1].y);
  o1.x = f2b(acc2[2].x); o1.y = f2b(acc2[2].y);
  o1.z = f2b(acc2[3].x); o1.w = f2b(acc2[3].y);
  ushort* op = outb + (uint)tok * 256u + (uint)(l * 8);
  *(ushort4*)op = o0;
  *(ushort4*)(op + 4) = o1;
}

// ---------------- LayerNorm over 256 (wave per row, 4 rows/block) -----------
template <int OUTF>
__global__ __launch_bounds__(256) void ln256(
    const ushort* __restrict__ in, const float* __restrict__ gg,
    const float* __restrict__ bb, ushort* __restrict__ outb,
    float* __restrict__ outf, int rows)
{
  const int wave = threadIdx.x >> 6, lane = threadIdx.x & 63;
  const int r = blockIdx.x * 4 + wave;
  if (r >= rows) return;
  const ushort* rowp = in + (size_t)r * 256;
  const ushort4 u = *(const ushort4*)(rowp + lane * 4);
  float v[4] = {b2f(u.x), b2f(u.y), b2f(u.z), b2f(u.w)};
  float s = v[0] + v[1] + v[2] + v[3];
  float s2 = v[0] * v[0] + v[1] * v[1] + v[2] * v[2] + v[3] * v[3];
#pragma unroll
  for (int o = 32; o > 0; o >>= 1) {
    s += __shfl_xor(s, o);
    s2 += __shfl_xor(s2, o);
  }
  const float mean = s * (1.f / 256.f);
  const float var = s2 * (1.f / 256.f) - mean * mean;
  const float rstd = rsqrtf(var + 1e-5f);
#pragma unroll
  for (int j = 0; j < 4; j++) {
    const int col = lane * 4 + j;
    const float o = (v[j] - mean) * rstd * gg[col] + bb[col];
    if (OUTF) outf[(size_t)r * 256 + col] = o;
    else outb[(size_t)r * 256 + col] = f2b(o);
  }
}

// ---------------------------------------------------------------------------
extern "C" void kernel_launch(void* const* d_in, const int* in_sizes, int n_in,
                              void* d_out, int out_size, void* d_ws, size_t ws_size,
                              hipStream_t stream)
{
  const float* src   = (const float*)d_in[0];
  const float* pos   = (const float*)d_in[1];
  const float* refp  = (const float*)d_in[2];
  const float* Wv    = (const float*)d_in[3];
  const float* bv    = (const float*)d_in[4];
  const float* Woff  = (const float*)d_in[5];
  const float* boff  = (const float*)d_in[6];
  const float* Wattn = (const float*)d_in[7];
  const float* battn = (const float*)d_in[8];
  const float* Wout  = (const float*)d_in[9];
  const float* bout  = (const float*)d_in[10];
  const float* g1    = (const float*)d_in[11];
  const float* b1    = (const float*)d_in[12];
  const float* Wff1  = (const float*)d_in[13];
  const float* bff1  = (const float*)d_in[14];
  const float* Wff2  = (const float*)d_in[15];
  const float* bff2  = (const float*)d_in[16];
  const float* g2    = (const float*)d_in[17];
  const float* b2    = (const float*)d_in[18];
  float* out = (float*)d_out;
  char* ws = (char*)d_ws;

  // workspace (bytes). A-buffers exact BLTOK-sized; GEMM A-reads up to MPAD
  // rows spill harmlessly into the next buffer (outputs row-guarded).
  // wv_t/wout_t live in dead A5 interior (attn_out head < 27MB; both consumed
  // before G4 writes h over all of A5).
  ushort* wcat_t = (ushort*)(ws + 0);            //  196608 (384x256)
  ushort* wff1_t = (ushort*)(ws + 196608);       //  524288
  ushort* wff2_t = (ushort*)(ws + 720896);       //  524288
  float*  bcat   = (float*)(ws + 1245184);       //    1536
  ushort* A1 = (ushort*)(ws + 1246720);          // src_bf        (BL x 256)
  ushort* A2 = (ushort*)(ws + 28126720);         // q_bf -> x_bf  (BL x 256)
  ushort* A3 = (ushort*)(ws + 55006720);         // value         (BL x 256)
  ushort* A4 = (ushort*)(ws + 81886720);         // offattn(320) -> xpre(256)
  ushort* A5 = (ushort*)(ws + 115486720);        // attn_out -> h (MPAD x 1024)
  ushort* wv_t   = (ushort*)(ws + 155486720);    //  131072 (A5 interior)
  ushort* wout_t = (ushort*)(ws + 155617792);    //  131072 (A5 interior)
  // end of A5: 223096832

  prep_weights<<<2946, 256, 0, stream>>>(Wv, Woff, Wattn, Wout, Wff1, Wff2,
                                         boff, battn,
                                         wv_t, wcat_t, wout_t, wff1_t, wff2_t, bcat);
  prep_act<<<BLTOK / 4, 256, 0, stream>>>(src, pos, A1, A2);
  // G1: value = src @ Wv + bv
  gemm64n<0><<<dim3(1, MPAD / 64), 256, 0, stream>>>(A1, wv_t, bv, nullptr,
                                                     A3, BLTOK, 256, 256, 256);
  // G2: offattn = q @ Wcat + bcat (N=320; chunk2 stages garbage B-rows, masked)
  gemm64n<0><<<dim3(2, MPAD / 64), 256, 0, stream>>>(A2, wcat_t, bcat, nullptr,
                                                     A4, BLTOK, 320, 320, 256);
  softmax12<<<(BLTOK * 8 + 255) / 256, 256, 0, stream>>>(A4);
  // attn_out -> A5 head
  deform_sample<<<(BLTOK + 7) / 8, 256, 0, stream>>>(A3, A4, refp, A5);
  // G3: xpre = src_bf + attn_out @ Wout + bout
  gemm64n<3><<<dim3(1, MPAD / 64), 256, 0, stream>>>(A5, wout_t, bout, A1,
                                                     A4, BLTOK, 256, 256, 256);
  ln256<0><<<BLTOK / 4, 256, 0, stream>>>(A4, g1, b1, A2, nullptr, BLTOK);
  // G4: h = relu(x @ Wff1 + bff1)
  gemm64n<2><<<dim3(4, MPAD / 64), 256, 0, stream>>>(A2, wff1_t, bff1, nullptr,
                                                     A5, BLTOK, 1024, 1024, 256);
  // G5: y = x + h @ Wff2 + bff2
  gemm64n<3><<<dim3(1, MPAD / 64), 256, 0, stream>>>(A5, wff2_t, bff2, A2,
                                                     A3, BLTOK, 256, 256, 1024);
  ln256<1><<<BLTOK / 4, 256, 0, stream>>>(A3, g2, b2, nullptr, out, BLTOK);
}